// Round 10
// baseline (456.294 us; speedup 1.0000x reference)
//
#include <hip/hip_runtime.h>

// LGAN layer on a fixed 8-ring graph, N=20000, D=128, MH=256.
// R10: full linear factoring. he is never materialized:
//   P_j[i] = relu(G[i]+G[i+j]+b1),  G = h@We1 (natural layout)
//   at = SA@We2 + 16 b2,  an = (SF-SA)@We2 + 84 b2
//   SA[w] = Q8[w] + sum_j P_j[w-j]
//   SF[w] = sum_{i=w-8}^{w} Q8[i] + sum_{m=1}^{7} Q_m[w+8-m]   (Q_m = j-prefix)
// paccum: per-wave 8 nodes, 24 rows x 8 j fully unrolled, 4 dims/lane,
//   writes SA and D=SF-SA in sigma-slot layout (slot base per lane l:
//   (l>>3)*32+(l&3)*8+((l>>2)&1)*4, so catgemm B-frags load contiguously).
// catgemm: [40000x256]@[256x128] with quarter-staged We2 (R9 structure).
// fuse_mlp/out_mlp unchanged (Wf1t back to natural rows).

#define NN 20000
#define NE 160000
#define DD 128
#define MHD 256

typedef __attribute__((ext_vector_type(8))) short short8;
typedef __attribute__((ext_vector_type(4))) short short4v;
typedef __attribute__((ext_vector_type(4))) float f32x4;

#define SWZ(row) (((row) & 7) << 3)

__device__ __forceinline__ float bf2f(short s) {
  return __builtin_bit_cast(float, (unsigned int)((unsigned short)s) << 16);
}
__device__ __forceinline__ short f2bf(float f) {
  unsigned int u = __builtin_bit_cast(unsigned int, f);
  u = (u + 0x7FFFu + ((u >> 16) & 1u)) >> 16;
  return (short)u;
}
__device__ __forceinline__ short8 zero8() {
  short8 z;
#pragma unroll
  for (int q = 0; q < 8; ++q) z[q] = 0;
  return z;
}

#define MFMA(a, b, c) __builtin_amdgcn_mfma_f32_16x16x32_bf16((a), (b), (c), 0, 0, 0)

// ============ Kernel A0: G = h @ We1, NATURAL bf16 columns =================
__global__ __launch_bounds__(256, 3) void g_gemm(
    const short* __restrict__ hbf, const short* __restrict__ wqA,
    short* __restrict__ G) {
  __shared__ __align__(16) short WS[8192];
  const int t = threadIdx.x;
  const int lane = t & 63, w = t >> 6;
  const int lr = lane & 15, lg = lane >> 4;
  const int rbase = blockIdx.x * 128 + w * 32;

  short8 xf[2][4];
#pragma unroll
  for (int rs = 0; rs < 2; ++rs) {
    int r = rbase + rs * 16 + lr;
    if (r >= NN) r = NN - 1;
    const short* hr = hbf + (size_t)r * DD;
#pragma unroll
    for (int kk = 0; kk < 4; ++kk)
      xf[rs][kk] = *(const short8*)&hr[kk * 32 + lg * 8];
  }

#pragma unroll 1
  for (int p = 0; p < 4; ++p) {
    {
      short8 stg[4];
#pragma unroll
      for (int c = 0; c < 4; ++c)
        stg[c] = *(const short8*)&wqA[p * 8192 + (c * 256 + t) * 8];
#pragma unroll
      for (int c = 0; c < 4; ++c) *(short8*)&WS[(c * 256 + t) * 8] = stg[c];
    }
    __syncthreads();
#pragma unroll
    for (int ct = 0; ct < 4; ++ct) {
      short8 aw[4];
#pragma unroll
      for (int kk = 0; kk < 4; ++kk)
        aw[kk] = *(const short8*)&WS[(ct * 16 + lr) * 128 +
                                     (((kk * 4 + lg) ^ lr) << 3)];
#pragma unroll
      for (int rs = 0; rs < 2; ++rs) {
        f32x4 a1 = {0.f, 0.f, 0.f, 0.f};
#pragma unroll
        for (int kk = 0; kk < 4; ++kk) a1 = MFMA(aw[kk], xf[rs][kk], a1);
        const int row = rbase + rs * 16 + lr;
        if (row < NN) {
          short4v o;
#pragma unroll
          for (int q = 0; q < 4; ++q) o[q] = f2bf(a1[q]);
          const int off = p * 64 + ct * 16 + 4 * lg;  // natural col
          *(short4v*)&G[(size_t)row * 256 + off] = o;
        }
      }
    }
    __syncthreads();
  }
}

// ============ Kernel A1: P-space window accumulation =======================
// Wave owns 8 nodes [nb, nb+8); lane l owns dims 4l..4l+3.
__global__ __launch_bounds__(256, 4) void paccum(
    const short* __restrict__ G, const float* __restrict__ be1,
    short* __restrict__ SA, short* __restrict__ Dout) {
  const int t = threadIdx.x;
  const int l = t & 63, wid = t >> 6;
  const int nb = blockIdx.x * 32 + wid * 8;
  const f32x4 b1 = *(const f32x4*)&be1[l * 4];

  float sa[8][4], sf[8][4];
#pragma unroll
  for (int w = 0; w < 8; ++w)
#pragma unroll
    for (int q = 0; q < 4; ++q) {
      sa[w][q] = 0.f;
      sf[w][q] = 0.f;
    }

#pragma unroll
  for (int ii = 0; ii < 24; ++ii) {
    int i = nb - 8 + ii;
    if (i < 0) i += NN;
    else if (i >= NN) i -= NN;
    short4v gi4 = *(const short4v*)&G[(size_t)i * 256 + l * 4];
    float gi[4];
#pragma unroll
    for (int q = 0; q < 4; ++q) gi[q] = bf2f(gi4[q]);
    float Q[4] = {0.f, 0.f, 0.f, 0.f};
#pragma unroll
    for (int j = 1; j <= 8; ++j) {
      int ij = i + j;
      if (ij >= NN) ij -= NN;
      short4v gj4 = *(const short4v*)&G[(size_t)ij * 256 + l * 4];
      float p[4];
#pragma unroll
      for (int q = 0; q < 4; ++q) {
        float x = gi[q] + bf2f(gj4[q]) + b1[q];
        p[q] = x > 0.f ? x : 0.f;
        Q[q] += p[q];
      }
      // P_j[i] -> SA[i+j]
      const int wSA = ii - 8 + j;
      if (wSA >= 0 && wSA < 8)
#pragma unroll
        for (int q = 0; q < 4; ++q) sa[wSA][q] += p[q];
      // Q_m[i] (m=j<=7) -> SF[i+j-8]
      if (j <= 7) {
        const int wF = ii - 16 + j;
        if (wF >= 0 && wF < 8)
#pragma unroll
          for (int q = 0; q < 4; ++q) sf[wF][q] += Q[q];
      }
    }
    // Q8[i] -> SA[i]
    const int iw = ii - 8;
    if (iw >= 0 && iw < 8)
#pragma unroll
      for (int q = 0; q < 4; ++q) sa[iw][q] += Q[q];
    // Q8[i] -> SF[w], w in [i, i+8]
#pragma unroll
    for (int s = 0; s <= 8; ++s) {
      const int wF = ii - 8 + s;
      if (wF >= 0 && wF < 8)
#pragma unroll
        for (int q = 0; q < 4; ++q) sf[wF][q] += Q[q];
    }
  }

  // sigma-slot write: lane l, dims 4l+q -> slot sb+q
  const int sb = (l >> 3) * 32 + (l & 3) * 8 + ((l >> 2) & 1) * 4;
#pragma unroll
  for (int w = 0; w < 8; ++w) {
    short4v oa, od;
#pragma unroll
    for (int q = 0; q < 4; ++q) {
      oa[q] = f2bf(sa[w][q]);
      od[q] = f2bf(sf[w][q] - sa[w][q]);
    }
    *(short4v*)&SA[(size_t)(nb + w) * 256 + sb] = oa;
    *(short4v*)&Dout[(size_t)(nb + w) * 256 + sb] = od;
  }
}

// ============ Kernel A2: cat = [SA@We2+16b2 ; D@We2+84b2] ==================
__global__ __launch_bounds__(256, 3) void catgemm(
    const short* __restrict__ SA, const short* __restrict__ Dm,
    const short* __restrict__ wqB, const float* __restrict__ be2,
    short* __restrict__ catb) {
  __shared__ __align__(16) short WS[8192];
  const int t = threadIdx.x;
  const int lane = t & 63, w = t >> 6;
  const int lr = lane & 15, lg = lane >> 4;
  const int vbase = blockIdx.x * 128 + w * 32;

  const short* srcp[2];
  int orow[2], dcb[2];
  float bm[2];
  bool ok[2];
#pragma unroll
  for (int rs = 0; rs < 2; ++rs) {
    int vr = vbase + rs * 16 + lr;
    ok[rs] = vr < 2 * NN;
    if (vr >= 2 * NN) vr = 2 * NN - 1;
    const bool isA = vr < NN;
    srcp[rs] = isA ? SA : Dm;
    orow[rs] = isA ? vr : vr - NN;
    bm[rs] = isA ? 16.0f : 84.0f;
    dcb[rs] = isA ? 0 : 128;
  }

  f32x4 acc[2][8];
#pragma unroll
  for (int rs = 0; rs < 2; ++rs)
#pragma unroll
    for (int ct2 = 0; ct2 < 8; ++ct2) acc[rs][ct2] = {0.f, 0.f, 0.f, 0.f};

#pragma unroll 1
  for (int p = 0; p < 4; ++p) {
    {
      short8 stg[4];
#pragma unroll
      for (int c = 0; c < 4; ++c)
        stg[c] = *(const short8*)&wqB[p * 8192 + (c * 256 + t) * 8];
#pragma unroll
      for (int c = 0; c < 4; ++c) *(short8*)&WS[(c * 256 + t) * 8] = stg[c];
    }
    __syncthreads();

    short8 pa[2][2];
#pragma unroll
    for (int rs = 0; rs < 2; ++rs)
#pragma unroll
      for (int kk2 = 0; kk2 < 2; ++kk2)
        pa[rs][kk2] = *(const short8*)&srcp[rs][(size_t)orow[rs] * 256 +
                                               p * 64 + kk2 * 32 + lg * 8];

#pragma unroll
    for (int kk2 = 0; kk2 < 2; ++kk2)
#pragma unroll
      for (int ct2 = 0; ct2 < 8; ++ct2) {
        short8 aw2 = *(const short8*)&WS[(ct2 * 16 + lr) * 64 +
                                         (((kk2 * 4 + lg) ^ (lr & 7)) << 3)];
        acc[0][ct2] = MFMA(aw2, pa[0][kk2], acc[0][ct2]);
        acc[1][ct2] = MFMA(aw2, pa[1][kk2], acc[1][ct2]);
      }
    __syncthreads();
  }

#pragma unroll
  for (int rs = 0; rs < 2; ++rs) {
    if (!ok[rs]) continue;
#pragma unroll
    for (int ct2 = 0; ct2 < 8; ++ct2) {
      const f32x4 bb = *(const f32x4*)&be2[ct2 * 16 + 4 * lg];
      short4v o;
#pragma unroll
      for (int q = 0; q < 4; ++q) o[q] = f2bf(acc[rs][ct2][q] + bm[rs] * bb[q]);
      *(short4v*)&catb[(size_t)orow[rs] * 256 + dcb[rs] + ct2 * 16 + 4 * lg] = o;
    }
  }
}

// ======== R1-style helpers (LDS Xs/H1s, XOR swizzle) for fuse/out ==========
template <int NK, int LDX>
__device__ __forceinline__ void stage1s(const short* Xs, short* H1s,
                                        const short* __restrict__ W1t,
                                        const float* __restrict__ b1, int lane,
                                        int wid) {
  constexpr int K1 = NK * 32;
  const int lr = lane & 15, lg = lane >> 4;
#pragma unroll
  for (int ct = 0; ct < 4; ++ct) {
    const int wc = wid * 64 + ct * 16;
    short8 aw[NK];
#pragma unroll
    for (int kk = 0; kk < NK; ++kk)
      aw[kk] = *(const short8*)&W1t[(wc + lr) * K1 + kk * 32 + lg * 8];
    const f32x4 bias = *(const f32x4*)&b1[wc + 4 * lg];
#pragma unroll
    for (int r = 0; r < 4; ++r) {
      const int row = r * 16 + lr;
      const int swz = SWZ(row);
      short8 bx[NK];
#pragma unroll
      for (int kk = 0; kk < NK; ++kk)
        bx[kk] = *(const short8*)&Xs[row * LDX + ((kk * 32 + lg * 8) ^ swz)];
      f32x4 acc = bias;
#pragma unroll
      for (int kk = 0; kk < NK; ++kk) acc = MFMA(aw[kk], bx[kk], acc);
      short4v o;
#pragma unroll
      for (int q = 0; q < 4; ++q) {
        float v = acc[q] > 0.f ? acc[q] : 0.f;
        o[q] = f2bf(v);
      }
      *(short4v*)&H1s[row * 256 + ((wc + 4 * lg) ^ swz)] = o;
    }
  }
}

__device__ __forceinline__ void stage2s(const short* H1s,
                                        const short* __restrict__ W2t,
                                        f32x4 (&acc)[2][4], int lane, int wid) {
  const int lr = lane & 15, lg = lane >> 4;
#pragma unroll
  for (int ct = 0; ct < 2; ++ct) {
    const int wc = wid * 32 + ct * 16;
    short8 aw[8];
#pragma unroll
    for (int kk = 0; kk < 8; ++kk)
      aw[kk] = *(const short8*)&W2t[(wc + lr) * 256 + kk * 32 + lg * 8];
#pragma unroll
    for (int r = 0; r < 4; ++r) {
      const int row = r * 16 + lr;
      const int swz = SWZ(row);
#pragma unroll
      for (int kk = 0; kk < 8; ++kk) {
        short8 bh = *(const short8*)&H1s[row * 256 + ((kk * 32 + lg * 8) ^ swz)];
        acc[ct][r] = MFMA(aw[kk], bh, acc[ct][r]);
      }
    }
  }
}

// ================= Kernel C: t = MLP_f(cat) + h @ W_r + b_r ================
__global__ __launch_bounds__(256) void fuse_mlp(
    const short* __restrict__ catb, const short* __restrict__ hbf,
    const short* __restrict__ Wf1t, const float* __restrict__ bf1,
    const short* __restrict__ Wf2t, const float* __restrict__ bf2,
    const short* __restrict__ Wrt, const float* __restrict__ br,
    short* __restrict__ tout) {
  __shared__ __align__(16) short Xs[64][256];
  __shared__ __align__(16) short H1s[64][256];
  const int t = threadIdx.x;
  const int vbase = blockIdx.x * 64;
  {
    const int r = t >> 2, sub = t & 3;
    const int v = vbase + r;
    const bool valid = v < NN;
    const int swz = SWZ(r);
#pragma unroll
    for (int c = 0; c < 8; ++c) {
      const int d0 = sub * 64 + c * 8;
      short8 x = valid ? *(const short8*)&catb[(size_t)v * 256 + d0] : zero8();
      *(short8*)&Xs[r][d0 ^ swz] = x;
    }
  }
  __syncthreads();
  const int lane = t & 63, wid = t >> 6;
  stage1s<8, 256>(&Xs[0][0], &H1s[0][0], Wf1t, bf1, lane, wid);
  __syncthreads();
  const int lr = lane & 15, lg = lane >> 4;
  f32x4 acc[2][4];
#pragma unroll
  for (int ct = 0; ct < 2; ++ct) {
    const int wc = wid * 32 + ct * 16 + 4 * lg;
    f32x4 b0 = *(const f32x4*)&br[wc];
    f32x4 b1v = *(const f32x4*)&bf2[wc];
    f32x4 bias = b0 + b1v;
#pragma unroll
    for (int r = 0; r < 4; ++r) acc[ct][r] = bias;
  }
#pragma unroll
  for (int ct = 0; ct < 2; ++ct) {
    const int wc = wid * 32 + ct * 16;
    short8 aw[4];
#pragma unroll
    for (int kk = 0; kk < 4; ++kk)
      aw[kk] = *(const short8*)&Wrt[(wc + lr) * DD + kk * 32 + lg * 8];
#pragma unroll
    for (int r = 0; r < 4; ++r) {
      int v = vbase + r * 16 + lr;
      if (v >= NN) v = 0;
#pragma unroll
      for (int kk = 0; kk < 4; ++kk) {
        short8 bh = *(const short8*)&hbf[(size_t)v * DD + kk * 32 + lg * 8];
        acc[ct][r] = MFMA(aw[kk], bh, acc[ct][r]);
      }
    }
  }
  stage2s(&H1s[0][0], Wf2t, acc, lane, wid);
#pragma unroll
  for (int ct = 0; ct < 2; ++ct)
#pragma unroll
    for (int r = 0; r < 4; ++r) {
      const int v = vbase + r * 16 + lr;
      if (v < NN) {
        short4v o;
#pragma unroll
        for (int q = 0; q < 4; ++q) o[q] = f2bf(acc[ct][r][q]);
        *(short4v*)&tout[(size_t)v * DD + wid * 32 + ct * 16 + 4 * lg] = o;
      }
    }
}

// ================= Kernel D: out = MLP_p(t), fp32 out ======================
__global__ __launch_bounds__(256) void out_mlp(
    const short* __restrict__ tin, const short* __restrict__ Wp1t,
    const float* __restrict__ bp1, const short* __restrict__ Wp2t,
    const float* __restrict__ bp2, float* __restrict__ out) {
  __shared__ __align__(16) short Xs[64][128];
  __shared__ __align__(16) short H1s[64][256];
  const int t = threadIdx.x;
  const int vbase = blockIdx.x * 64;
  {
    const int r = t >> 2, sub = t & 3;
    const int v = vbase + r;
    const bool valid = v < NN;
    const int swz = SWZ(r);
#pragma unroll
    for (int c = 0; c < 4; ++c) {
      const int d0 = (sub * 4 + c) * 8;
      short8 x = valid ? *(const short8*)&tin[(size_t)v * DD + d0] : zero8();
      *(short8*)&Xs[r][d0 ^ swz] = x;
    }
  }
  __syncthreads();
  const int lane = t & 63, wid = t >> 6;
  stage1s<4, 128>(&Xs[0][0], &H1s[0][0], Wp1t, bp1, lane, wid);
  __syncthreads();
  const int lr = lane & 15, lg = lane >> 4;
  f32x4 acc[2][4];
#pragma unroll
  for (int ct = 0; ct < 2; ++ct) {
    const f32x4 bias = *(const f32x4*)&bp2[wid * 32 + ct * 16 + 4 * lg];
#pragma unroll
    for (int r = 0; r < 4; ++r) acc[ct][r] = bias;
  }
  stage2s(&H1s[0][0], Wp2t, acc, lane, wid);
#pragma unroll
  for (int ct = 0; ct < 2; ++ct)
#pragma unroll
    for (int r = 0; r < 4; ++r) {
      const int v = vbase + r * 16 + lr;
      if (v < NN)
        *(f32x4*)&out[(size_t)v * DD + wid * 32 + ct * 16 + 4 * lg] = acc[ct][r];
    }
}

// ================= conversions =============================================
__global__ __launch_bounds__(256) void cvt_h(const float* __restrict__ src,
                                             short* __restrict__ dst) {
  const size_t id = (size_t)(blockIdx.x * 256 + threadIdx.x) * 8;
  float4 a = *(const float4*)&src[id];
  float4 b = *(const float4*)&src[id + 4];
  short8 o;
  o[0] = f2bf(a.x); o[1] = f2bf(a.y); o[2] = f2bf(a.z); o[3] = f2bf(a.w);
  o[4] = f2bf(b.x); o[5] = f2bf(b.y); o[6] = f2bf(b.z); o[7] = f2bf(b.w);
  *(short8*)&dst[id] = o;
}

// sigma: slot s -> logical mid index
__device__ __forceinline__ int klog_of_slot(int s) {
  return ((s >> 5) << 5) + (((s >> 2) & 1) << 4) + (((s >> 3) & 3) << 2) + (s & 3);
}

// pool layout (shorts):
//   [0]      wqA: 4 x We1 quarter [64 mids][128 k] chunk-swz   = 32768
//   [32768]  wqB: 4 x We2 quarter [128 o][64 slots] swz+sigma  = 32768
//   [65536]  Wf1t [256][256] k-contig (natural rows)
//   [131072] Wf2t [128][256] k-contig
//   [163840] Wrt  [128][128] k-contig
//   [180224] Wp1t [256][128] k-contig
//   [212992] Wp2t [128][256] k-contig                          (ends 245760)
__global__ __launch_bounds__(256) void cvt_weights(
    const float* __restrict__ We1, const float* __restrict__ We2,
    const float* __restrict__ Wf1, const float* __restrict__ Wf2,
    const float* __restrict__ Wr, const float* __restrict__ Wp1,
    const float* __restrict__ Wp2, short* __restrict__ dst) {
  const int id = blockIdx.x * 256 + threadIdx.x;
  float v;
  if (id < 32768) {                       // wqA
    const int p = id >> 13, r = id & 8191;
    const int lm = r >> 7, e = r & 127;
    const int k = (((e >> 3) ^ (lm & 15)) << 3) | (e & 7);
    v = We1[k * 256 + p * 64 + lm];
  } else if (id < 65536) {                // wqB
    const int l = id - 32768;
    const int p = l >> 13, i2 = l & 8191;
    const int o = i2 >> 6, e = i2 & 63;
    const int s = (((e >> 3) ^ (o & 7)) << 3) | (e & 7);
    v = We2[(p * 64 + klog_of_slot(s)) * 128 + o];
  } else if (id < 131072) {               // Wf1t natural
    const int l = id - 65536;
    v = Wf1[(l & 255) * 256 + (l >> 8)];
  } else if (id < 163840) {               // Wf2t
    const int l = id - 131072;
    v = Wf2[(l & 255) * 128 + (l >> 8)];
  } else if (id < 180224) {               // Wrt
    const int l = id - 163840;
    v = Wr[(l & 127) * 128 + (l >> 7)];
  } else if (id < 212992) {               // Wp1t
    const int l = id - 180224;
    v = Wp1[(l & 127) * 256 + (l >> 7)];
  } else {                                // Wp2t
    const int l = id - 212992;
    v = Wp2[(l & 255) * 128 + (l >> 8)];
  }
  dst[id] = f2bf(v);
}

extern "C" void kernel_launch(void* const* d_in, const int* in_sizes, int n_in,
                              void* d_out, int out_size, void* d_ws,
                              size_t ws_size, hipStream_t stream) {
  const float* h = (const float*)d_in[0];
  const float* We1 = (const float*)d_in[4];
  const float* be1 = (const float*)d_in[5];
  const float* We2 = (const float*)d_in[6];
  const float* be2 = (const float*)d_in[7];
  const float* Wf1 = (const float*)d_in[8];
  const float* bf1 = (const float*)d_in[9];
  const float* Wf2 = (const float*)d_in[10];
  const float* bf2 = (const float*)d_in[11];
  const float* Wr = (const float*)d_in[12];
  const float* br = (const float*)d_in[13];
  const float* Wp1 = (const float*)d_in[14];
  const float* bp1 = (const float*)d_in[15];
  const float* Wp2 = (const float*)d_in[16];
  const float* bp2 = (const float*)d_in[17];

  char* ws = (char*)d_ws;
  short* hbf = (short*)ws;                      // 20000*128*2   = 5,120,000
  short* SA = (short*)(ws + 5120000);           // 20000*256*2   = 10,240,000
  short* Dm = (short*)(ws + 15360000);          // 20000*256*2   = 10,240,000
  short* catb = (short*)(ws + 46080000);        // 20000*256*2   = 10,240,000
  short* tbuf = (short*)(ws + 56320000);        // 20000*128*2   = 5,120,000
  short* wpool = (short*)(ws + 61440000);       // 245760*2      = 491,520
  short* wqA = wpool;
  short* wqB = wpool + 32768;
  short* Wf1t = wpool + 65536;
  short* Wf2t = Wf1t + 65536;
  short* Wrt = Wf2t + 32768;
  short* Wp1t = Wrt + 16384;
  short* Wp2t = Wp1t + 32768;
  short* G = catb;  // overlay: G dead before catgemm writes catb

  cvt_h<<<1250, 256, 0, stream>>>(h, hbf);
  cvt_weights<<<960, 256, 0, stream>>>(We1, We2, Wf1, Wf2, Wr, Wp1, Wp2, wpool);
  g_gemm<<<(NN + 127) / 128, 256, 0, stream>>>(hbf, wqA, G);
  paccum<<<NN / 32, 256, 0, stream>>>(G, be1, SA, Dm);
  catgemm<<<(2 * NN + 127) / 128, 256, 0, stream>>>(SA, Dm, wqB, be2, catb);
  fuse_mlp<<<(NN + 63) / 64, 256, 0, stream>>>(catb, hbf, Wf1t, bf1, Wf2t, bf2,
                                               Wrt, br, tbuf);
  out_mlp<<<(NN + 63) / 64, 256, 0, stream>>>(tbuf, Wp1t, bp1, Wp2t, bp2,
                                              (float*)d_out);
}

// Round 11
// 281.830 us; speedup vs baseline: 1.6190x; 1.6190x over previous
//
#include <hip/hip_runtime.h>

// LGAN layer on a fixed 8-ring graph, N=20000, D=128, MH=256.
// R11: R10's P-space factoring (verified) + sliding-window paccum:
//   win[9] = G[i..i+8] in registers (bf16), ONE new row load per ii step
//   (33 loads/wave vs 216). Algebra unchanged:
//   P_j[i] = relu(G[i]+G[i+j]+b1); at = SA@We2+16b2; an = (SF-SA)@We2+84b2
//   SA[w] = Q8[w] + sum_j P_j[w-j]
//   SF[w] = sum_{i=w-8}^{w} Q8[i] + sum_{m=1}^{7} Q_m[w+8-m]

#define NN 20000
#define NE 160000
#define DD 128
#define MHD 256

typedef __attribute__((ext_vector_type(8))) short short8;
typedef __attribute__((ext_vector_type(4))) short short4v;
typedef __attribute__((ext_vector_type(4))) float f32x4;

#define SWZ(row) (((row) & 7) << 3)

__device__ __forceinline__ float bf2f(short s) {
  return __builtin_bit_cast(float, (unsigned int)((unsigned short)s) << 16);
}
__device__ __forceinline__ short f2bf(float f) {
  unsigned int u = __builtin_bit_cast(unsigned int, f);
  u = (u + 0x7FFFu + ((u >> 16) & 1u)) >> 16;
  return (short)u;
}
__device__ __forceinline__ short8 zero8() {
  short8 z;
#pragma unroll
  for (int q = 0; q < 8; ++q) z[q] = 0;
  return z;
}

#define MFMA(a, b, c) __builtin_amdgcn_mfma_f32_16x16x32_bf16((a), (b), (c), 0, 0, 0)

// ============ Kernel A0: G = h @ We1, NATURAL bf16 columns =================
__global__ __launch_bounds__(256, 3) void g_gemm(
    const short* __restrict__ hbf, const short* __restrict__ wqA,
    short* __restrict__ G) {
  __shared__ __align__(16) short WS[8192];
  const int t = threadIdx.x;
  const int lane = t & 63, w = t >> 6;
  const int lr = lane & 15, lg = lane >> 4;
  const int rbase = blockIdx.x * 128 + w * 32;

  short8 xf[2][4];
#pragma unroll
  for (int rs = 0; rs < 2; ++rs) {
    int r = rbase + rs * 16 + lr;
    if (r >= NN) r = NN - 1;
    const short* hr = hbf + (size_t)r * DD;
#pragma unroll
    for (int kk = 0; kk < 4; ++kk)
      xf[rs][kk] = *(const short8*)&hr[kk * 32 + lg * 8];
  }

#pragma unroll 1
  for (int p = 0; p < 4; ++p) {
    {
      short8 stg[4];
#pragma unroll
      for (int c = 0; c < 4; ++c)
        stg[c] = *(const short8*)&wqA[p * 8192 + (c * 256 + t) * 8];
#pragma unroll
      for (int c = 0; c < 4; ++c) *(short8*)&WS[(c * 256 + t) * 8] = stg[c];
    }
    __syncthreads();
#pragma unroll
    for (int ct = 0; ct < 4; ++ct) {
      short8 aw[4];
#pragma unroll
      for (int kk = 0; kk < 4; ++kk)
        aw[kk] = *(const short8*)&WS[(ct * 16 + lr) * 128 +
                                     (((kk * 4 + lg) ^ lr) << 3)];
#pragma unroll
      for (int rs = 0; rs < 2; ++rs) {
        f32x4 a1 = {0.f, 0.f, 0.f, 0.f};
#pragma unroll
        for (int kk = 0; kk < 4; ++kk) a1 = MFMA(aw[kk], xf[rs][kk], a1);
        const int row = rbase + rs * 16 + lr;
        if (row < NN) {
          short4v o;
#pragma unroll
          for (int q = 0; q < 4; ++q) o[q] = f2bf(a1[q]);
          const int off = p * 64 + ct * 16 + 4 * lg;  // natural col
          *(short4v*)&G[(size_t)row * 256 + off] = o;
        }
      }
    }
    __syncthreads();
  }
}

// ============ Kernel A1: P-space window accumulation (sliding window) ======
// Wave owns 8 nodes [nb, nb+8); lane l owns dims 4l..4l+3.
__global__ __launch_bounds__(256, 3) void paccum(
    const short* __restrict__ G, const float* __restrict__ be1,
    short* __restrict__ SA, short* __restrict__ Dout) {
  const int t = threadIdx.x;
  const int l = t & 63, wid = t >> 6;
  const int nb = blockIdx.x * 32 + wid * 8;
  const f32x4 b1 = *(const f32x4*)&be1[l * 4];

  float sa[8][4], sf[8][4];
#pragma unroll
  for (int w = 0; w < 8; ++w)
#pragma unroll
    for (int q = 0; q < 4; ++q) {
      sa[w][q] = 0.f;
      sf[w][q] = 0.f;
    }

  // window: win[k] holds lane's dims of G[i+k], i = current row
  short4v win[9];
#pragma unroll
  for (int k = 0; k < 9; ++k) {
    int r = nb - 8 + k;
    if (r < 0) r += NN;
    win[k] = *(const short4v*)&G[(size_t)r * 256 + l * 4];
  }

#pragma unroll
  for (int ii = 0; ii < 24; ++ii) {
    // i = nb - 8 + ii; win[0]=G[i], win[j]=G[i+j]
    float gi[4];
#pragma unroll
    for (int q = 0; q < 4; ++q) gi[q] = bf2f(win[0][q]);
    float Q[4] = {0.f, 0.f, 0.f, 0.f};
#pragma unroll
    for (int j = 1; j <= 8; ++j) {
      float p[4];
#pragma unroll
      for (int q = 0; q < 4; ++q) {
        float x = gi[q] + bf2f(win[j][q]) + b1[q];
        p[q] = x > 0.f ? x : 0.f;
        Q[q] += p[q];
      }
      // P_j[i] -> SA[i+j]
      const int wSA = ii - 8 + j;
      if (wSA >= 0 && wSA < 8)
#pragma unroll
        for (int q = 0; q < 4; ++q) sa[wSA][q] += p[q];
      // Q_m[i] (m=j<=7) -> SF[i+j-8]
      if (j <= 7) {
        const int wF = ii - 16 + j;
        if (wF >= 0 && wF < 8)
#pragma unroll
          for (int q = 0; q < 4; ++q) sf[wF][q] += Q[q];
      }
    }
    // Q8[i] -> SA[i]
    const int iw = ii - 8;
    if (iw >= 0 && iw < 8)
#pragma unroll
      for (int q = 0; q < 4; ++q) sa[iw][q] += Q[q];
    // Q8[i] -> SF[w], w in [i, i+8]
#pragma unroll
    for (int s = 0; s <= 8; ++s) {
      const int wF = ii - 8 + s;
      if (wF >= 0 && wF < 8)
#pragma unroll
        for (int q = 0; q < 4; ++q) sf[wF][q] += Q[q];
    }
    // slide window: one new row
    if (ii < 23) {
#pragma unroll
      for (int k = 0; k < 8; ++k) win[k] = win[k + 1];
      int r = nb + 1 + ii;
      if (r >= NN) r -= NN;
      win[8] = *(const short4v*)&G[(size_t)r * 256 + l * 4];
    }
  }

  // sigma-slot write: lane l, dims 4l+q -> slot sb+q
  const int sb = (l >> 3) * 32 + (l & 3) * 8 + ((l >> 2) & 1) * 4;
#pragma unroll
  for (int w = 0; w < 8; ++w) {
    short4v oa, od;
#pragma unroll
    for (int q = 0; q < 4; ++q) {
      oa[q] = f2bf(sa[w][q]);
      od[q] = f2bf(sf[w][q] - sa[w][q]);
    }
    *(short4v*)&SA[(size_t)(nb + w) * 256 + sb] = oa;
    *(short4v*)&Dout[(size_t)(nb + w) * 256 + sb] = od;
  }
}

// ============ Kernel A2: cat = [SA@We2+16b2 ; D@We2+84b2] ==================
__global__ __launch_bounds__(256, 3) void catgemm(
    const short* __restrict__ SA, const short* __restrict__ Dm,
    const short* __restrict__ wqB, const float* __restrict__ be2,
    short* __restrict__ catb) {
  __shared__ __align__(16) short WS[8192];
  const int t = threadIdx.x;
  const int lane = t & 63, w = t >> 6;
  const int lr = lane & 15, lg = lane >> 4;
  const int vbase = blockIdx.x * 128 + w * 32;

  const short* srcp[2];
  int orow[2], dcb[2];
  float bm[2];
  bool ok[2];
#pragma unroll
  for (int rs = 0; rs < 2; ++rs) {
    int vr = vbase + rs * 16 + lr;
    ok[rs] = vr < 2 * NN;
    if (vr >= 2 * NN) vr = 2 * NN - 1;
    const bool isA = vr < NN;
    srcp[rs] = isA ? SA : Dm;
    orow[rs] = isA ? vr : vr - NN;
    bm[rs] = isA ? 16.0f : 84.0f;
    dcb[rs] = isA ? 0 : 128;
  }

  f32x4 acc[2][8];
#pragma unroll
  for (int rs = 0; rs < 2; ++rs)
#pragma unroll
    for (int ct2 = 0; ct2 < 8; ++ct2) acc[rs][ct2] = {0.f, 0.f, 0.f, 0.f};

#pragma unroll 1
  for (int p = 0; p < 4; ++p) {
    {
      short8 stg[4];
#pragma unroll
      for (int c = 0; c < 4; ++c)
        stg[c] = *(const short8*)&wqB[p * 8192 + (c * 256 + t) * 8];
#pragma unroll
      for (int c = 0; c < 4; ++c) *(short8*)&WS[(c * 256 + t) * 8] = stg[c];
    }
    __syncthreads();

    short8 pa[2][2];
#pragma unroll
    for (int rs = 0; rs < 2; ++rs)
#pragma unroll
      for (int kk2 = 0; kk2 < 2; ++kk2)
        pa[rs][kk2] = *(const short8*)&srcp[rs][(size_t)orow[rs] * 256 +
                                               p * 64 + kk2 * 32 + lg * 8];

#pragma unroll
    for (int kk2 = 0; kk2 < 2; ++kk2)
#pragma unroll
      for (int ct2 = 0; ct2 < 8; ++ct2) {
        short8 aw2 = *(const short8*)&WS[(ct2 * 16 + lr) * 64 +
                                         (((kk2 * 4 + lg) ^ (lr & 7)) << 3)];
        acc[0][ct2] = MFMA(aw2, pa[0][kk2], acc[0][ct2]);
        acc[1][ct2] = MFMA(aw2, pa[1][kk2], acc[1][ct2]);
      }
    __syncthreads();
  }

#pragma unroll
  for (int rs = 0; rs < 2; ++rs) {
    if (!ok[rs]) continue;
#pragma unroll
    for (int ct2 = 0; ct2 < 8; ++ct2) {
      const f32x4 bb = *(const f32x4*)&be2[ct2 * 16 + 4 * lg];
      short4v o;
#pragma unroll
      for (int q = 0; q < 4; ++q) o[q] = f2bf(acc[rs][ct2][q] + bm[rs] * bb[q]);
      *(short4v*)&catb[(size_t)orow[rs] * 256 + dcb[rs] + ct2 * 16 + 4 * lg] = o;
    }
  }
}

// ======== R1-style helpers (LDS Xs/H1s, XOR swizzle) for fuse/out ==========
template <int NK, int LDX>
__device__ __forceinline__ void stage1s(const short* Xs, short* H1s,
                                        const short* __restrict__ W1t,
                                        const float* __restrict__ b1, int lane,
                                        int wid) {
  constexpr int K1 = NK * 32;
  const int lr = lane & 15, lg = lane >> 4;
#pragma unroll
  for (int ct = 0; ct < 4; ++ct) {
    const int wc = wid * 64 + ct * 16;
    short8 aw[NK];
#pragma unroll
    for (int kk = 0; kk < NK; ++kk)
      aw[kk] = *(const short8*)&W1t[(wc + lr) * K1 + kk * 32 + lg * 8];
    const f32x4 bias = *(const f32x4*)&b1[wc + 4 * lg];
#pragma unroll
    for (int r = 0; r < 4; ++r) {
      const int row = r * 16 + lr;
      const int swz = SWZ(row);
      short8 bx[NK];
#pragma unroll
      for (int kk = 0; kk < NK; ++kk)
        bx[kk] = *(const short8*)&Xs[row * LDX + ((kk * 32 + lg * 8) ^ swz)];
      f32x4 acc = bias;
#pragma unroll
      for (int kk = 0; kk < NK; ++kk) acc = MFMA(aw[kk], bx[kk], acc);
      short4v o;
#pragma unroll
      for (int q = 0; q < 4; ++q) {
        float v = acc[q] > 0.f ? acc[q] : 0.f;
        o[q] = f2bf(v);
      }
      *(short4v*)&H1s[row * 256 + ((wc + 4 * lg) ^ swz)] = o;
    }
  }
}

__device__ __forceinline__ void stage2s(const short* H1s,
                                        const short* __restrict__ W2t,
                                        f32x4 (&acc)[2][4], int lane, int wid) {
  const int lr = lane & 15, lg = lane >> 4;
#pragma unroll
  for (int ct = 0; ct < 2; ++ct) {
    const int wc = wid * 32 + ct * 16;
    short8 aw[8];
#pragma unroll
    for (int kk = 0; kk < 8; ++kk)
      aw[kk] = *(const short8*)&W2t[(wc + lr) * 256 + kk * 32 + lg * 8];
#pragma unroll
    for (int r = 0; r < 4; ++r) {
      const int row = r * 16 + lr;
      const int swz = SWZ(row);
#pragma unroll
      for (int kk = 0; kk < 8; ++kk) {
        short8 bh = *(const short8*)&H1s[row * 256 + ((kk * 32 + lg * 8) ^ swz)];
        acc[ct][r] = MFMA(aw[kk], bh, acc[ct][r]);
      }
    }
  }
}

// ================= Kernel C: t = MLP_f(cat) + h @ W_r + b_r ================
__global__ __launch_bounds__(256) void fuse_mlp(
    const short* __restrict__ catb, const short* __restrict__ hbf,
    const short* __restrict__ Wf1t, const float* __restrict__ bf1,
    const short* __restrict__ Wf2t, const float* __restrict__ bf2,
    const short* __restrict__ Wrt, const float* __restrict__ br,
    short* __restrict__ tout) {
  __shared__ __align__(16) short Xs[64][256];
  __shared__ __align__(16) short H1s[64][256];
  const int t = threadIdx.x;
  const int vbase = blockIdx.x * 64;
  {
    const int r = t >> 2, sub = t & 3;
    const int v = vbase + r;
    const bool valid = v < NN;
    const int swz = SWZ(r);
#pragma unroll
    for (int c = 0; c < 8; ++c) {
      const int d0 = sub * 64 + c * 8;
      short8 x = valid ? *(const short8*)&catb[(size_t)v * 256 + d0] : zero8();
      *(short8*)&Xs[r][d0 ^ swz] = x;
    }
  }
  __syncthreads();
  const int lane = t & 63, wid = t >> 6;
  stage1s<8, 256>(&Xs[0][0], &H1s[0][0], Wf1t, bf1, lane, wid);
  __syncthreads();
  const int lr = lane & 15, lg = lane >> 4;
  f32x4 acc[2][4];
#pragma unroll
  for (int ct = 0; ct < 2; ++ct) {
    const int wc = wid * 32 + ct * 16 + 4 * lg;
    f32x4 b0 = *(const f32x4*)&br[wc];
    f32x4 b1v = *(const f32x4*)&bf2[wc];
    f32x4 bias = b0 + b1v;
#pragma unroll
    for (int r = 0; r < 4; ++r) acc[ct][r] = bias;
  }
#pragma unroll
  for (int ct = 0; ct < 2; ++ct) {
    const int wc = wid * 32 + ct * 16;
    short8 aw[4];
#pragma unroll
    for (int kk = 0; kk < 4; ++kk)
      aw[kk] = *(const short8*)&Wrt[(wc + lr) * DD + kk * 32 + lg * 8];
#pragma unroll
    for (int r = 0; r < 4; ++r) {
      int v = vbase + r * 16 + lr;
      if (v >= NN) v = 0;
#pragma unroll
      for (int kk = 0; kk < 4; ++kk) {
        short8 bh = *(const short8*)&hbf[(size_t)v * DD + kk * 32 + lg * 8];
        acc[ct][r] = MFMA(aw[kk], bh, acc[ct][r]);
      }
    }
  }
  stage2s(&H1s[0][0], Wf2t, acc, lane, wid);
#pragma unroll
  for (int ct = 0; ct < 2; ++ct)
#pragma unroll
    for (int r = 0; r < 4; ++r) {
      const int v = vbase + r * 16 + lr;
      if (v < NN) {
        short4v o;
#pragma unroll
        for (int q = 0; q < 4; ++q) o[q] = f2bf(acc[ct][r][q]);
        *(short4v*)&tout[(size_t)v * DD + wid * 32 + ct * 16 + 4 * lg] = o;
      }
    }
}

// ================= Kernel D: out = MLP_p(t), fp32 out ======================
__global__ __launch_bounds__(256) void out_mlp(
    const short* __restrict__ tin, const short* __restrict__ Wp1t,
    const float* __restrict__ bp1, const short* __restrict__ Wp2t,
    const float* __restrict__ bp2, float* __restrict__ out) {
  __shared__ __align__(16) short Xs[64][128];
  __shared__ __align__(16) short H1s[64][256];
  const int t = threadIdx.x;
  const int vbase = blockIdx.x * 64;
  {
    const int r = t >> 2, sub = t & 3;
    const int v = vbase + r;
    const bool valid = v < NN;
    const int swz = SWZ(r);
#pragma unroll
    for (int c = 0; c < 4; ++c) {
      const int d0 = (sub * 4 + c) * 8;
      short8 x = valid ? *(const short8*)&tin[(size_t)v * DD + d0] : zero8();
      *(short8*)&Xs[r][d0 ^ swz] = x;
    }
  }
  __syncthreads();
  const int lane = t & 63, wid = t >> 6;
  stage1s<4, 128>(&Xs[0][0], &H1s[0][0], Wp1t, bp1, lane, wid);
  __syncthreads();
  const int lr = lane & 15, lg = lane >> 4;
  f32x4 acc[2][4];
#pragma unroll
  for (int ct = 0; ct < 2; ++ct) {
    const f32x4 bias = *(const f32x4*)&bp2[wid * 32 + ct * 16 + 4 * lg];
#pragma unroll
    for (int r = 0; r < 4; ++r) acc[ct][r] = bias;
  }
  stage2s(&H1s[0][0], Wp2t, acc, lane, wid);
#pragma unroll
  for (int ct = 0; ct < 2; ++ct)
#pragma unroll
    for (int r = 0; r < 4; ++r) {
      const int v = vbase + r * 16 + lr;
      if (v < NN)
        *(f32x4*)&out[(size_t)v * DD + wid * 32 + ct * 16 + 4 * lg] = acc[ct][r];
    }
}

// ================= conversions =============================================
__global__ __launch_bounds__(256) void cvt_h(const float* __restrict__ src,
                                             short* __restrict__ dst) {
  const size_t id = (size_t)(blockIdx.x * 256 + threadIdx.x) * 8;
  float4 a = *(const float4*)&src[id];
  float4 b = *(const float4*)&src[id + 4];
  short8 o;
  o[0] = f2bf(a.x); o[1] = f2bf(a.y); o[2] = f2bf(a.z); o[3] = f2bf(a.w);
  o[4] = f2bf(b.x); o[5] = f2bf(b.y); o[6] = f2bf(b.z); o[7] = f2bf(b.w);
  *(short8*)&dst[id] = o;
}

// sigma: slot s -> logical mid index
__device__ __forceinline__ int klog_of_slot(int s) {
  return ((s >> 5) << 5) + (((s >> 2) & 1) << 4) + (((s >> 3) & 3) << 2) + (s & 3);
}

// pool layout (shorts):
//   [0]      wqA: 4 x We1 quarter [64 mids][128 k] chunk-swz   = 32768
//   [32768]  wqB: 4 x We2 quarter [128 o][64 slots] swz+sigma  = 32768
//   [65536]  Wf1t [256][256] k-contig (natural rows)
//   [131072] Wf2t [128][256] k-contig
//   [163840] Wrt  [128][128] k-contig
//   [180224] Wp1t [256][128] k-contig
//   [212992] Wp2t [128][256] k-contig                          (ends 245760)
__global__ __launch_bounds__(256) void cvt_weights(
    const float* __restrict__ We1, const float* __restrict__ We2,
    const float* __restrict__ Wf1, const float* __restrict__ Wf2,
    const float* __restrict__ Wr, const float* __restrict__ Wp1,
    const float* __restrict__ Wp2, short* __restrict__ dst) {
  const int id = blockIdx.x * 256 + threadIdx.x;
  float v;
  if (id < 32768) {                       // wqA
    const int p = id >> 13, r = id & 8191;
    const int lm = r >> 7, e = r & 127;
    const int k = (((e >> 3) ^ (lm & 15)) << 3) | (e & 7);
    v = We1[k * 256 + p * 64 + lm];
  } else if (id < 65536) {                // wqB
    const int l = id - 32768;
    const int p = l >> 13, i2 = l & 8191;
    const int o = i2 >> 6, e = i2 & 63;
    const int s = (((e >> 3) ^ (o & 7)) << 3) | (e & 7);
    v = We2[(p * 64 + klog_of_slot(s)) * 128 + o];
  } else if (id < 131072) {               // Wf1t natural
    const int l = id - 65536;
    v = Wf1[(l & 255) * 256 + (l >> 8)];
  } else if (id < 163840) {               // Wf2t
    const int l = id - 131072;
    v = Wf2[(l & 255) * 128 + (l >> 8)];
  } else if (id < 180224) {               // Wrt
    const int l = id - 163840;
    v = Wr[(l & 127) * 128 + (l >> 7)];
  } else if (id < 212992) {               // Wp1t
    const int l = id - 180224;
    v = Wp1[(l & 127) * 256 + (l >> 7)];
  } else {                                // Wp2t
    const int l = id - 212992;
    v = Wp2[(l & 255) * 128 + (l >> 8)];
  }
  dst[id] = f2bf(v);
}

extern "C" void kernel_launch(void* const* d_in, const int* in_sizes, int n_in,
                              void* d_out, int out_size, void* d_ws,
                              size_t ws_size, hipStream_t stream) {
  const float* h = (const float*)d_in[0];
  const float* We1 = (const float*)d_in[4];
  const float* be1 = (const float*)d_in[5];
  const float* We2 = (const float*)d_in[6];
  const float* be2 = (const float*)d_in[7];
  const float* Wf1 = (const float*)d_in[8];
  const float* bf1 = (const float*)d_in[9];
  const float* Wf2 = (const float*)d_in[10];
  const float* bf2 = (const float*)d_in[11];
  const float* Wr = (const float*)d_in[12];
  const float* br = (const float*)d_in[13];
  const float* Wp1 = (const float*)d_in[14];
  const float* bp1 = (const float*)d_in[15];
  const float* Wp2 = (const float*)d_in[16];
  const float* bp2 = (const float*)d_in[17];

  char* ws = (char*)d_ws;
  short* hbf = (short*)ws;                      // 20000*128*2   = 5,120,000
  short* SA = (short*)(ws + 5120000);           // 20000*256*2   = 10,240,000
  short* Dm = (short*)(ws + 15360000);          // 20000*256*2   = 10,240,000
  short* catb = (short*)(ws + 46080000);        // 20000*256*2   = 10,240,000
  short* tbuf = (short*)(ws + 56320000);        // 20000*128*2   = 5,120,000
  short* wpool = (short*)(ws + 61440000);       // 245760*2      = 491,520
  short* wqA = wpool;
  short* wqB = wpool + 32768;
  short* Wf1t = wpool + 65536;
  short* Wf2t = Wf1t + 65536;
  short* Wrt = Wf2t + 32768;
  short* Wp1t = Wrt + 16384;
  short* Wp2t = Wp1t + 32768;
  short* G = catb;  // overlay: G dead before catgemm writes catb

  cvt_h<<<1250, 256, 0, stream>>>(h, hbf);
  cvt_weights<<<960, 256, 0, stream>>>(We1, We2, Wf1, Wf2, Wr, Wp1, Wp2, wpool);
  g_gemm<<<(NN + 127) / 128, 256, 0, stream>>>(hbf, wqA, G);
  paccum<<<NN / 32, 256, 0, stream>>>(G, be1, SA, Dm);
  catgemm<<<(2 * NN + 127) / 128, 256, 0, stream>>>(SA, Dm, wqB, be2, catb);
  fuse_mlp<<<(NN + 63) / 64, 256, 0, stream>>>(catb, hbf, Wf1t, bf1, Wf2t, bf2,
                                               Wrt, br, tbuf);
  out_mlp<<<(NN + 63) / 64, 256, 0, stream>>>(tbuf, Wp1t, bp1, Wp2t, bp2,
                                              (float*)d_out);
}

// Round 12
// 95.986 us; speedup vs baseline: 4.7538x; 2.9362x over previous
//
#include <hip/hip_runtime.h>

// LGAN layer on a fixed 8-ring graph, N=20000, D=128, MH=256.
// R12: R11 algebra (verified), paccum rebuilt with MACRO-forced full unroll
//   so every sa/sf/win index is a compile-time constant (rule #20: the
//   pragma-unroll version left arrays runtime-indexed -> scratch -> 353MB
//   of spill writes). f32x4 vector accumulators, 24 static steps.

#define NN 20000
#define NE 160000
#define DD 128
#define MHD 256

typedef __attribute__((ext_vector_type(8))) short short8;
typedef __attribute__((ext_vector_type(4))) short short4v;
typedef __attribute__((ext_vector_type(4))) float f32x4;

#define SWZ(row) (((row) & 7) << 3)

__device__ __forceinline__ float bf2f(short s) {
  return __builtin_bit_cast(float, (unsigned int)((unsigned short)s) << 16);
}
__device__ __forceinline__ short f2bf(float f) {
  unsigned int u = __builtin_bit_cast(unsigned int, f);
  u = (u + 0x7FFFu + ((u >> 16) & 1u)) >> 16;
  return (short)u;
}
__device__ __forceinline__ short8 zero8() {
  short8 z;
#pragma unroll
  for (int q = 0; q < 8; ++q) z[q] = 0;
  return z;
}

#define MFMA(a, b, c) __builtin_amdgcn_mfma_f32_16x16x32_bf16((a), (b), (c), 0, 0, 0)

// ============ Kernel A0: G = h @ We1, NATURAL bf16 columns =================
__global__ __launch_bounds__(256, 3) void g_gemm(
    const short* __restrict__ hbf, const short* __restrict__ wqA,
    short* __restrict__ G) {
  __shared__ __align__(16) short WS[8192];
  const int t = threadIdx.x;
  const int lane = t & 63, w = t >> 6;
  const int lr = lane & 15, lg = lane >> 4;
  const int rbase = blockIdx.x * 128 + w * 32;

  short8 xf[2][4];
#pragma unroll
  for (int rs = 0; rs < 2; ++rs) {
    int r = rbase + rs * 16 + lr;
    if (r >= NN) r = NN - 1;
    const short* hr = hbf + (size_t)r * DD;
#pragma unroll
    for (int kk = 0; kk < 4; ++kk)
      xf[rs][kk] = *(const short8*)&hr[kk * 32 + lg * 8];
  }

#pragma unroll 1
  for (int p = 0; p < 4; ++p) {
    {
      short8 stg[4];
#pragma unroll
      for (int c = 0; c < 4; ++c)
        stg[c] = *(const short8*)&wqA[p * 8192 + (c * 256 + t) * 8];
#pragma unroll
      for (int c = 0; c < 4; ++c) *(short8*)&WS[(c * 256 + t) * 8] = stg[c];
    }
    __syncthreads();
#pragma unroll
    for (int ct = 0; ct < 4; ++ct) {
      short8 aw[4];
#pragma unroll
      for (int kk = 0; kk < 4; ++kk)
        aw[kk] = *(const short8*)&WS[(ct * 16 + lr) * 128 +
                                     (((kk * 4 + lg) ^ lr) << 3)];
#pragma unroll
      for (int rs = 0; rs < 2; ++rs) {
        f32x4 a1 = {0.f, 0.f, 0.f, 0.f};
#pragma unroll
        for (int kk = 0; kk < 4; ++kk) a1 = MFMA(aw[kk], xf[rs][kk], a1);
        const int row = rbase + rs * 16 + lr;
        if (row < NN) {
          short4v o;
#pragma unroll
          for (int q = 0; q < 4; ++q) o[q] = f2bf(a1[q]);
          const int off = p * 64 + ct * 16 + 4 * lg;  // natural col
          *(short4v*)&G[(size_t)row * 256 + off] = o;
        }
      }
    }
    __syncthreads();
  }
}

// ============ Kernel A1: P-space window accumulation (static unroll) =======
// Wave owns 8 nodes [nb, nb+8); lane l owns dims 4l..4l+3.
#define LOADROW(dst, ridx)                                          \
  {                                                                 \
    int r_ = (ridx);                                                \
    if (r_ < 0) r_ += NN;                                           \
    else if (r_ >= NN) r_ -= NN;                                    \
    short4v g_ = *(const short4v*)&G[(size_t)r_ * 256 + l * 4];     \
    (dst)[0] = bf2f(g_[0]);                                         \
    (dst)[1] = bf2f(g_[1]);                                         \
    (dst)[2] = bf2f(g_[2]);                                         \
    (dst)[3] = bf2f(g_[3]);                                         \
  }

#define QJ(ii, j)                                                       \
  {                                                                     \
    f32x4 p = win[j] + gib;                                             \
    p[0] = fmaxf(p[0], 0.f);                                            \
    p[1] = fmaxf(p[1], 0.f);                                            \
    p[2] = fmaxf(p[2], 0.f);                                            \
    p[3] = fmaxf(p[3], 0.f);                                            \
    Q += p;                                                             \
    if ((ii) - 8 + (j) >= 0 && (ii) - 8 + (j) < 8)                      \
      sa[((ii) - 8 + (j)) & 7] += p;                                    \
    if ((j) <= 7 && (ii) - 16 + (j) >= 0 && (ii) - 16 + (j) < 8)        \
      sf[((ii) - 16 + (j)) & 7] += Q;                                   \
  }

#define SFS(ii, s)                                                      \
  if ((ii) - 8 + (s) >= 0 && (ii) - 8 + (s) < 8)                        \
    sf[((ii) - 8 + (s)) & 7] += Q;

#define PSTEP(ii)                                                       \
  {                                                                     \
    const f32x4 gib = win[0] + b1;                                      \
    f32x4 Q = {0.f, 0.f, 0.f, 0.f};                                     \
    QJ(ii, 1) QJ(ii, 2) QJ(ii, 3) QJ(ii, 4)                             \
    QJ(ii, 5) QJ(ii, 6) QJ(ii, 7) QJ(ii, 8)                             \
    if ((ii) >= 8 && (ii) < 16) sa[((ii) - 8) & 7] += Q;                \
    SFS(ii, 0) SFS(ii, 1) SFS(ii, 2) SFS(ii, 3) SFS(ii, 4)              \
    SFS(ii, 5) SFS(ii, 6) SFS(ii, 7) SFS(ii, 8)                         \
    if ((ii) < 23) {                                                    \
      win[0] = win[1]; win[1] = win[2]; win[2] = win[3];                \
      win[3] = win[4]; win[4] = win[5]; win[5] = win[6];                \
      win[6] = win[7]; win[7] = win[8];                                 \
      LOADROW(win[8], nb + 1 + (ii));                                   \
    }                                                                   \
  }

__global__ __launch_bounds__(256, 3) void paccum(
    const short* __restrict__ G, const float* __restrict__ be1,
    short* __restrict__ SA, short* __restrict__ Dout) {
  const int t = threadIdx.x;
  const int l = t & 63, wid = t >> 6;
  const int nb = blockIdx.x * 32 + wid * 8;
  const f32x4 b1 = *(const f32x4*)&be1[l * 4];

  f32x4 sa[8], sf[8];
#pragma unroll
  for (int w = 0; w < 8; ++w) {
    sa[w] = {0.f, 0.f, 0.f, 0.f};
    sf[w] = {0.f, 0.f, 0.f, 0.f};
  }

  f32x4 win[9];
  LOADROW(win[0], nb - 8) LOADROW(win[1], nb - 7) LOADROW(win[2], nb - 6)
  LOADROW(win[3], nb - 5) LOADROW(win[4], nb - 4) LOADROW(win[5], nb - 3)
  LOADROW(win[6], nb - 2) LOADROW(win[7], nb - 1) LOADROW(win[8], nb)

  PSTEP(0)  PSTEP(1)  PSTEP(2)  PSTEP(3)  PSTEP(4)  PSTEP(5)
  PSTEP(6)  PSTEP(7)  PSTEP(8)  PSTEP(9)  PSTEP(10) PSTEP(11)
  PSTEP(12) PSTEP(13) PSTEP(14) PSTEP(15) PSTEP(16) PSTEP(17)
  PSTEP(18) PSTEP(19) PSTEP(20) PSTEP(21) PSTEP(22) PSTEP(23)

  // sigma-slot write: lane l, dims 4l+q -> slot sb+q
  const int sb = (l >> 3) * 32 + (l & 3) * 8 + ((l >> 2) & 1) * 4;
#pragma unroll
  for (int w = 0; w < 8; ++w) {
    short4v oa, od;
#pragma unroll
    for (int q = 0; q < 4; ++q) {
      oa[q] = f2bf(sa[w][q]);
      od[q] = f2bf(sf[w][q] - sa[w][q]);
    }
    *(short4v*)&SA[(size_t)(nb + w) * 256 + sb] = oa;
    *(short4v*)&Dout[(size_t)(nb + w) * 256 + sb] = od;
  }
}

// ============ Kernel A2: cat = [SA@We2+16b2 ; D@We2+84b2] ==================
__global__ __launch_bounds__(256, 3) void catgemm(
    const short* __restrict__ SA, const short* __restrict__ Dm,
    const short* __restrict__ wqB, const float* __restrict__ be2,
    short* __restrict__ catb) {
  __shared__ __align__(16) short WS[8192];
  const int t = threadIdx.x;
  const int lane = t & 63, w = t >> 6;
  const int lr = lane & 15, lg = lane >> 4;
  const int vbase = blockIdx.x * 128 + w * 32;

  const short* srcp[2];
  int orow[2], dcb[2];
  float bm[2];
  bool ok[2];
#pragma unroll
  for (int rs = 0; rs < 2; ++rs) {
    int vr = vbase + rs * 16 + lr;
    ok[rs] = vr < 2 * NN;
    if (vr >= 2 * NN) vr = 2 * NN - 1;
    const bool isA = vr < NN;
    srcp[rs] = isA ? SA : Dm;
    orow[rs] = isA ? vr : vr - NN;
    bm[rs] = isA ? 16.0f : 84.0f;
    dcb[rs] = isA ? 0 : 128;
  }

  f32x4 acc[2][8];
#pragma unroll
  for (int rs = 0; rs < 2; ++rs)
#pragma unroll
    for (int ct2 = 0; ct2 < 8; ++ct2) acc[rs][ct2] = {0.f, 0.f, 0.f, 0.f};

#pragma unroll 1
  for (int p = 0; p < 4; ++p) {
    {
      short8 stg[4];
#pragma unroll
      for (int c = 0; c < 4; ++c)
        stg[c] = *(const short8*)&wqB[p * 8192 + (c * 256 + t) * 8];
#pragma unroll
      for (int c = 0; c < 4; ++c) *(short8*)&WS[(c * 256 + t) * 8] = stg[c];
    }
    __syncthreads();

    short8 pa[2][2];
#pragma unroll
    for (int rs = 0; rs < 2; ++rs)
#pragma unroll
      for (int kk2 = 0; kk2 < 2; ++kk2)
        pa[rs][kk2] = *(const short8*)&srcp[rs][(size_t)orow[rs] * 256 +
                                               p * 64 + kk2 * 32 + lg * 8];

#pragma unroll
    for (int kk2 = 0; kk2 < 2; ++kk2)
#pragma unroll
      for (int ct2 = 0; ct2 < 8; ++ct2) {
        short8 aw2 = *(const short8*)&WS[(ct2 * 16 + lr) * 64 +
                                         (((kk2 * 4 + lg) ^ (lr & 7)) << 3)];
        acc[0][ct2] = MFMA(aw2, pa[0][kk2], acc[0][ct2]);
        acc[1][ct2] = MFMA(aw2, pa[1][kk2], acc[1][ct2]);
      }
    __syncthreads();
  }

#pragma unroll
  for (int rs = 0; rs < 2; ++rs) {
    if (!ok[rs]) continue;
#pragma unroll
    for (int ct2 = 0; ct2 < 8; ++ct2) {
      const f32x4 bb = *(const f32x4*)&be2[ct2 * 16 + 4 * lg];
      short4v o;
#pragma unroll
      for (int q = 0; q < 4; ++q) o[q] = f2bf(acc[rs][ct2][q] + bm[rs] * bb[q]);
      *(short4v*)&catb[(size_t)orow[rs] * 256 + dcb[rs] + ct2 * 16 + 4 * lg] = o;
    }
  }
}

// ======== R1-style helpers (LDS Xs/H1s, XOR swizzle) for fuse/out ==========
template <int NK, int LDX>
__device__ __forceinline__ void stage1s(const short* Xs, short* H1s,
                                        const short* __restrict__ W1t,
                                        const float* __restrict__ b1, int lane,
                                        int wid) {
  constexpr int K1 = NK * 32;
  const int lr = lane & 15, lg = lane >> 4;
#pragma unroll
  for (int ct = 0; ct < 4; ++ct) {
    const int wc = wid * 64 + ct * 16;
    short8 aw[NK];
#pragma unroll
    for (int kk = 0; kk < NK; ++kk)
      aw[kk] = *(const short8*)&W1t[(wc + lr) * K1 + kk * 32 + lg * 8];
    const f32x4 bias = *(const f32x4*)&b1[wc + 4 * lg];
#pragma unroll
    for (int r = 0; r < 4; ++r) {
      const int row = r * 16 + lr;
      const int swz = SWZ(row);
      short8 bx[NK];
#pragma unroll
      for (int kk = 0; kk < NK; ++kk)
        bx[kk] = *(const short8*)&Xs[row * LDX + ((kk * 32 + lg * 8) ^ swz)];
      f32x4 acc = bias;
#pragma unroll
      for (int kk = 0; kk < NK; ++kk) acc = MFMA(aw[kk], bx[kk], acc);
      short4v o;
#pragma unroll
      for (int q = 0; q < 4; ++q) {
        float v = acc[q] > 0.f ? acc[q] : 0.f;
        o[q] = f2bf(v);
      }
      *(short4v*)&H1s[row * 256 + ((wc + 4 * lg) ^ swz)] = o;
    }
  }
}

__device__ __forceinline__ void stage2s(const short* H1s,
                                        const short* __restrict__ W2t,
                                        f32x4 (&acc)[2][4], int lane, int wid) {
  const int lr = lane & 15, lg = lane >> 4;
#pragma unroll
  for (int ct = 0; ct < 2; ++ct) {
    const int wc = wid * 32 + ct * 16;
    short8 aw[8];
#pragma unroll
    for (int kk = 0; kk < 8; ++kk)
      aw[kk] = *(const short8*)&W2t[(wc + lr) * 256 + kk * 32 + lg * 8];
#pragma unroll
    for (int r = 0; r < 4; ++r) {
      const int row = r * 16 + lr;
      const int swz = SWZ(row);
#pragma unroll
      for (int kk = 0; kk < 8; ++kk) {
        short8 bh = *(const short8*)&H1s[row * 256 + ((kk * 32 + lg * 8) ^ swz)];
        acc[ct][r] = MFMA(aw[kk], bh, acc[ct][r]);
      }
    }
  }
}

// ================= Kernel C: t = MLP_f(cat) + h @ W_r + b_r ================
__global__ __launch_bounds__(256) void fuse_mlp(
    const short* __restrict__ catb, const short* __restrict__ hbf,
    const short* __restrict__ Wf1t, const float* __restrict__ bf1,
    const short* __restrict__ Wf2t, const float* __restrict__ bf2,
    const short* __restrict__ Wrt, const float* __restrict__ br,
    short* __restrict__ tout) {
  __shared__ __align__(16) short Xs[64][256];
  __shared__ __align__(16) short H1s[64][256];
  const int t = threadIdx.x;
  const int vbase = blockIdx.x * 64;
  {
    const int r = t >> 2, sub = t & 3;
    const int v = vbase + r;
    const bool valid = v < NN;
    const int swz = SWZ(r);
#pragma unroll
    for (int c = 0; c < 8; ++c) {
      const int d0 = sub * 64 + c * 8;
      short8 x = valid ? *(const short8*)&catb[(size_t)v * 256 + d0] : zero8();
      *(short8*)&Xs[r][d0 ^ swz] = x;
    }
  }
  __syncthreads();
  const int lane = t & 63, wid = t >> 6;
  stage1s<8, 256>(&Xs[0][0], &H1s[0][0], Wf1t, bf1, lane, wid);
  __syncthreads();
  const int lr = lane & 15, lg = lane >> 4;
  f32x4 acc[2][4];
#pragma unroll
  for (int ct = 0; ct < 2; ++ct) {
    const int wc = wid * 32 + ct * 16 + 4 * lg;
    f32x4 b0 = *(const f32x4*)&br[wc];
    f32x4 b1v = *(const f32x4*)&bf2[wc];
    f32x4 bias = b0 + b1v;
#pragma unroll
    for (int r = 0; r < 4; ++r) acc[ct][r] = bias;
  }
#pragma unroll
  for (int ct = 0; ct < 2; ++ct) {
    const int wc = wid * 32 + ct * 16;
    short8 aw[4];
#pragma unroll
    for (int kk = 0; kk < 4; ++kk)
      aw[kk] = *(const short8*)&Wrt[(wc + lr) * DD + kk * 32 + lg * 8];
#pragma unroll
    for (int r = 0; r < 4; ++r) {
      int v = vbase + r * 16 + lr;
      if (v >= NN) v = 0;
#pragma unroll
      for (int kk = 0; kk < 4; ++kk) {
        short8 bh = *(const short8*)&hbf[(size_t)v * DD + kk * 32 + lg * 8];
        acc[ct][r] = MFMA(aw[kk], bh, acc[ct][r]);
      }
    }
  }
  stage2s(&H1s[0][0], Wf2t, acc, lane, wid);
#pragma unroll
  for (int ct = 0; ct < 2; ++ct)
#pragma unroll
    for (int r = 0; r < 4; ++r) {
      const int v = vbase + r * 16 + lr;
      if (v < NN) {
        short4v o;
#pragma unroll
        for (int q = 0; q < 4; ++q) o[q] = f2bf(acc[ct][r][q]);
        *(short4v*)&tout[(size_t)v * DD + wid * 32 + ct * 16 + 4 * lg] = o;
      }
    }
}

// ================= Kernel D: out = MLP_p(t), fp32 out ======================
__global__ __launch_bounds__(256) void out_mlp(
    const short* __restrict__ tin, const short* __restrict__ Wp1t,
    const float* __restrict__ bp1, const short* __restrict__ Wp2t,
    const float* __restrict__ bp2, float* __restrict__ out) {
  __shared__ __align__(16) short Xs[64][128];
  __shared__ __align__(16) short H1s[64][256];
  const int t = threadIdx.x;
  const int vbase = blockIdx.x * 64;
  {
    const int r = t >> 2, sub = t & 3;
    const int v = vbase + r;
    const bool valid = v < NN;
    const int swz = SWZ(r);
#pragma unroll
    for (int c = 0; c < 4; ++c) {
      const int d0 = (sub * 4 + c) * 8;
      short8 x = valid ? *(const short8*)&tin[(size_t)v * DD + d0] : zero8();
      *(short8*)&Xs[r][d0 ^ swz] = x;
    }
  }
  __syncthreads();
  const int lane = t & 63, wid = t >> 6;
  stage1s<4, 128>(&Xs[0][0], &H1s[0][0], Wp1t, bp1, lane, wid);
  __syncthreads();
  const int lr = lane & 15, lg = lane >> 4;
  f32x4 acc[2][4];
#pragma unroll
  for (int ct = 0; ct < 2; ++ct) {
    const f32x4 bias = *(const f32x4*)&bp2[wid * 32 + ct * 16 + 4 * lg];
#pragma unroll
    for (int r = 0; r < 4; ++r) acc[ct][r] = bias;
  }
  stage2s(&H1s[0][0], Wp2t, acc, lane, wid);
#pragma unroll
  for (int ct = 0; ct < 2; ++ct)
#pragma unroll
    for (int r = 0; r < 4; ++r) {
      const int v = vbase + r * 16 + lr;
      if (v < NN)
        *(f32x4*)&out[(size_t)v * DD + wid * 32 + ct * 16 + 4 * lg] = acc[ct][r];
    }
}

// ================= conversions =============================================
__global__ __launch_bounds__(256) void cvt_h(const float* __restrict__ src,
                                             short* __restrict__ dst) {
  const size_t id = (size_t)(blockIdx.x * 256 + threadIdx.x) * 8;
  float4 a = *(const float4*)&src[id];
  float4 b = *(const float4*)&src[id + 4];
  short8 o;
  o[0] = f2bf(a.x); o[1] = f2bf(a.y); o[2] = f2bf(a.z); o[3] = f2bf(a.w);
  o[4] = f2bf(b.x); o[5] = f2bf(b.y); o[6] = f2bf(b.z); o[7] = f2bf(b.w);
  *(short8*)&dst[id] = o;
}

// sigma: slot s -> logical mid index
__device__ __forceinline__ int klog_of_slot(int s) {
  return ((s >> 5) << 5) + (((s >> 2) & 1) << 4) + (((s >> 3) & 3) << 2) + (s & 3);
}

// pool layout (shorts):
//   [0]      wqA: 4 x We1 quarter [64 mids][128 k] chunk-swz   = 32768
//   [32768]  wqB: 4 x We2 quarter [128 o][64 slots] swz+sigma  = 32768
//   [65536]  Wf1t [256][256] k-contig (natural rows)
//   [131072] Wf2t [128][256] k-contig
//   [163840] Wrt  [128][128] k-contig
//   [180224] Wp1t [256][128] k-contig
//   [212992] Wp2t [128][256] k-contig                          (ends 245760)
__global__ __launch_bounds__(256) void cvt_weights(
    const float* __restrict__ We1, const float* __restrict__ We2,
    const float* __restrict__ Wf1, const float* __restrict__ Wf2,
    const float* __restrict__ Wr, const float* __restrict__ Wp1,
    const float* __restrict__ Wp2, short* __restrict__ dst) {
  const int id = blockIdx.x * 256 + threadIdx.x;
  float v;
  if (id < 32768) {                       // wqA
    const int p = id >> 13, r = id & 8191;
    const int lm = r >> 7, e = r & 127;
    const int k = (((e >> 3) ^ (lm & 15)) << 3) | (e & 7);
    v = We1[k * 256 + p * 64 + lm];
  } else if (id < 65536) {                // wqB
    const int l = id - 32768;
    const int p = l >> 13, i2 = l & 8191;
    const int o = i2 >> 6, e = i2 & 63;
    const int s = (((e >> 3) ^ (o & 7)) << 3) | (e & 7);
    v = We2[(p * 64 + klog_of_slot(s)) * 128 + o];
  } else if (id < 131072) {               // Wf1t natural
    const int l = id - 65536;
    v = Wf1[(l & 255) * 256 + (l >> 8)];
  } else if (id < 163840) {               // Wf2t
    const int l = id - 131072;
    v = Wf2[(l & 255) * 128 + (l >> 8)];
  } else if (id < 180224) {               // Wrt
    const int l = id - 163840;
    v = Wr[(l & 127) * 128 + (l >> 7)];
  } else if (id < 212992) {               // Wp1t
    const int l = id - 180224;
    v = Wp1[(l & 127) * 256 + (l >> 7)];
  } else {                                // Wp2t
    const int l = id - 212992;
    v = Wp2[(l & 255) * 128 + (l >> 8)];
  }
  dst[id] = f2bf(v);
}

extern "C" void kernel_launch(void* const* d_in, const int* in_sizes, int n_in,
                              void* d_out, int out_size, void* d_ws,
                              size_t ws_size, hipStream_t stream) {
  const float* h = (const float*)d_in[0];
  const float* We1 = (const float*)d_in[4];
  const float* be1 = (const float*)d_in[5];
  const float* We2 = (const float*)d_in[6];
  const float* be2 = (const float*)d_in[7];
  const float* Wf1 = (const float*)d_in[8];
  const float* bf1 = (const float*)d_in[9];
  const float* Wf2 = (const float*)d_in[10];
  const float* bf2 = (const float*)d_in[11];
  const float* Wr = (const float*)d_in[12];
  const float* br = (const float*)d_in[13];
  const float* Wp1 = (const float*)d_in[14];
  const float* bp1 = (const float*)d_in[15];
  const float* Wp2 = (const float*)d_in[16];
  const float* bp2 = (const float*)d_in[17];

  char* ws = (char*)d_ws;
  short* hbf = (short*)ws;                      // 20000*128*2   = 5,120,000
  short* SA = (short*)(ws + 5120000);           // 20000*256*2   = 10,240,000
  short* Dm = (short*)(ws + 15360000);          // 20000*256*2   = 10,240,000
  short* catb = (short*)(ws + 46080000);        // 20000*256*2   = 10,240,000
  short* tbuf = (short*)(ws + 56320000);        // 20000*128*2   = 5,120,000
  short* wpool = (short*)(ws + 61440000);       // 245760*2      = 491,520
  short* wqA = wpool;
  short* wqB = wpool + 32768;
  short* Wf1t = wpool + 65536;
  short* Wf2t = Wf1t + 65536;
  short* Wrt = Wf2t + 32768;
  short* Wp1t = Wrt + 16384;
  short* Wp2t = Wp1t + 32768;
  short* G = catb;  // overlay: G dead before catgemm writes catb

  cvt_h<<<1250, 256, 0, stream>>>(h, hbf);
  cvt_weights<<<960, 256, 0, stream>>>(We1, We2, Wf1, Wf2, Wr, Wp1, Wp2, wpool);
  g_gemm<<<(NN + 127) / 128, 256, 0, stream>>>(hbf, wqA, G);
  paccum<<<NN / 32, 256, 0, stream>>>(G, be1, SA, Dm);
  catgemm<<<(2 * NN + 127) / 128, 256, 0, stream>>>(SA, Dm, wqB, be2, catb);
  fuse_mlp<<<(NN + 63) / 64, 256, 0, stream>>>(catb, hbf, Wf1t, bf1, Wf2t, bf2,
                                               Wrt, br, tbuf);
  out_mlp<<<(NN + 63) / 64, 256, 0, stream>>>(tbuf, Wp1t, bp1, Wp2t, bp2,
                                              (float*)d_out);
}